// Round 1
// baseline (1531.971 us; speedup 1.0000x reference)
//
#include <hip/hip_runtime.h>
#include <math.h>

#define D 8
#define ZDIM 16
#define HID 200
#define EPS 0.1f
#define B 8          // samples per workgroup
#define NTHREADS 256

// ---------------------------------------------------------------------------
// Transpose W1, W2 (200x200) into workspace for coalesced backward matvecs.
// ---------------------------------------------------------------------------
__global__ void transpose_k(const float* __restrict__ W1,
                            const float* __restrict__ W2,
                            float* __restrict__ W1T,
                            float* __restrict__ W2T)
{
    int idx = blockIdx.x * NTHREADS + threadIdx.x;
    if (idx < HID * HID) {
        int i = idx / HID, j = idx % HID;
        W1T[j * HID + i] = W1[idx];
        W2T[j * HID + i] = W2[idx];
    }
}

// acc[b] = sum_i xs[b*HID+i] * W[i*HID + j]   (xs in LDS, W in global/L2)
__device__ __forceinline__ void matvec_acc(const float* __restrict__ W,
                                           const float* __restrict__ xs,
                                           int j, float* __restrict__ acc)
{
#pragma unroll
    for (int b = 0; b < B; ++b) acc[b] = 0.f;
    const float* wp = W + j;
#pragma unroll 2
    for (int i = 0; i < HID; i += 4) {
        const float wa = wp[0];
        const float wb = wp[HID];
        const float wc = wp[2 * HID];
        const float wd = wp[3 * HID];
        wp += 4 * HID;
#pragma unroll
        for (int b = 0; b < B; ++b) {
            const float4 x = *reinterpret_cast<const float4*>(xs + b * HID + i);
            float a = acc[b];
            a = fmaf(x.x, wa, a);
            a = fmaf(x.y, wb, a);
            a = fmaf(x.z, wc, a);
            a = fmaf(x.w, wd, a);
            acc[b] = a;
        }
    }
}

// softplus value + sigmoid with one exp
__device__ __forceinline__ void act_(float x, float& sp, float& sg)
{
    float e = __expf(-fabsf(x));
    float r = 1.0f / (1.0f + e);
    sg = (x >= 0.f) ? r : (1.0f - r);
    sp = fmaxf(x, 0.f) + __logf(1.f + e);
}

__global__ void __launch_bounds__(NTHREADS, 2)
lnn_main(const float* __restrict__ z,
         const float* __restrict__ W0, const float* __restrict__ b0,
         const float* __restrict__ W1, const float* __restrict__ b1,
         const float* __restrict__ W2, const float* __restrict__ b2,
         const float* __restrict__ W3,
         const float* __restrict__ W1T, const float* __restrict__ W2T,
         float* __restrict__ out)
{
    __shared__ alignas(16) float p0s[B * HID];
    __shared__ alignas(16) float p1s[B * HID];
    __shared__ alignas(16) float c2s[B * HID];
    __shared__ alignas(16) float u1s[B * HID];
    __shared__ alignas(16) float u0s[B * HID];
    __shared__ alignas(16) float tA[B * HID];
    __shared__ alignas(16) float tB[B * HID];
    __shared__ alignas(16) float w0k[D * HID];   // rows D..2D-1 of W0 (tangent seeds)
    __shared__ float zsh[B * ZDIM];
    __shared__ float gsh[B * ZDIM];
    __shared__ float Hr[B * D * ZDIM];           // Hr[b][k][m] = H[D+k][m]

    const int tid = threadIdx.x;
    const int s0  = blockIdx.x * B;

    for (int idx = tid; idx < B * ZDIM; idx += NTHREADS) zsh[idx] = z[s0 * ZDIM + idx];
    for (int idx = tid; idx < D * HID; idx += NTHREADS) w0k[idx] = W0[D * HID + idx];
    __syncthreads();

    float acc[B];

    // ---- F0: a0 = z @ W0 + b0 ; h0 -> tA, sigmoid(a0) -> p0s ----
    if (tid < HID) {
        const int j = tid;
        float w[ZDIM];
#pragma unroll
        for (int k = 0; k < ZDIM; ++k) w[k] = W0[k * HID + j];
        const float bb = b0[j];
#pragma unroll
        for (int b = 0; b < B; ++b) {
            float a = bb;
#pragma unroll
            for (int k = 0; k < ZDIM; ++k) a = fmaf(zsh[b * ZDIM + k], w[k], a);
            float sp, sg; act_(a, sp, sg);
            tA[b * HID + j]  = sp;
            p0s[b * HID + j] = sg;
        }
    }
    __syncthreads();

    // ---- F1: a1 = h0 @ W1 + b1 ; h1 -> tB, sigmoid(a1) -> p1s ----
    if (tid < HID) {
        matvec_acc(W1, tA, tid, acc);
        const float bb = b1[tid];
#pragma unroll
        for (int b = 0; b < B; ++b) {
            float sp, sg; act_(acc[b] + bb, sp, sg);
            tB[b * HID + tid]  = sp;
            p1s[b * HID + tid] = sg;
        }
    }
    __syncthreads();

    // ---- F2: a2 = h1 @ W2 + b2 ; d2 = w3*sig(a2) -> tA, c2 = w3*sig'(a2) -> c2s ----
    if (tid < HID) {
        matvec_acc(W2, tB, tid, acc);
        const float bb  = b2[tid];
        const float w3v = W3[tid];
#pragma unroll
        for (int b = 0; b < B; ++b) {
            float a = acc[b] + bb;
            float e = __expf(-fabsf(a));
            float r = 1.f / (1.f + e);
            float sg = (a >= 0.f) ? r : (1.f - r);
            c2s[b * HID + tid] = w3v * sg * (1.f - sg);
            tA[b * HID + tid]  = w3v * sg;                 // d2
        }
    }
    __syncthreads();

    // ---- B1: u1 = W2 d2 ; d1 = u1*p1 -> tB ----
    if (tid < HID) {
        matvec_acc(W2T, tA, tid, acc);
#pragma unroll
        for (int b = 0; b < B; ++b) {
            u1s[b * HID + tid] = acc[b];
            tB[b * HID + tid]  = acc[b] * p1s[b * HID + tid];
        }
    }
    __syncthreads();

    // ---- B0: u0 = W1 d1 ; d0 = u0*p0 -> tA ----
    if (tid < HID) {
        matvec_acc(W1T, tB, tid, acc);
#pragma unroll
        for (int b = 0; b < B; ++b) {
            u0s[b * HID + tid] = acc[b];
            tA[b * HID + tid]  = acc[b] * p0s[b * HID + tid];
        }
    }
    __syncthreads();

    // ---- G: g[m] = sum_i W0[m,i] * d0[i]  (threads (b,m), b<8) ----
    if (tid < B * ZDIM) {
        const int b = tid >> 4, m = tid & 15;
        float s = 0.f;
        for (int i = 0; i < HID; i += 4) {
            const float4 x  = *reinterpret_cast<const float4*>(tA + b * HID + i);
            const float4 wv = *reinterpret_cast<const float4*>(W0 + m * HID + i);
            s += x.x * wv.x + x.y * wv.y + x.z * wv.z + x.w * wv.w;
        }
        gsh[b * ZDIM + m] = s;
    }
    __syncthreads();

    // ---- Tangent loop: 8 HVPs ----
    for (int k = 0; k < D; ++k) {
        // T1: th0 = p0 * t0 -> tA
        for (int idx = tid; idx < B * HID; idx += NTHREADS) {
            int i = idx % HID;
            tA[idx] = p0s[idx] * w0k[k * HID + i];
        }
        __syncthreads();

        // T2: t1 = th0 @ W1 -> tB (saved); th1 = p1*t1 -> tA
        if (tid < HID) matvec_acc(W1, tA, tid, acc);
        __syncthreads();
        if (tid < HID) {
#pragma unroll
            for (int b = 0; b < B; ++b) {
                tB[b * HID + tid] = acc[b];
                tA[b * HID + tid] = acc[b] * p1s[b * HID + tid];
            }
        }
        __syncthreads();

        // T3: t2 = th1 @ W2 ; d2dot = c2*t2 -> tA
        if (tid < HID) matvec_acc(W2, tA, tid, acc);
        __syncthreads();
        if (tid < HID) {
#pragma unroll
            for (int b = 0; b < B; ++b)
                tA[b * HID + tid] = acc[b] * c2s[b * HID + tid];
        }
        __syncthreads();

        // T4: v1 = W2 d2dot ; d1dot = v1*p1 + u1*q1*t1 -> tA
        if (tid < HID) matvec_acc(W2T, tA, tid, acc);
        __syncthreads();
        if (tid < HID) {
#pragma unroll
            for (int b = 0; b < B; ++b) {
                float p1v = p1s[b * HID + tid];
                float q1  = p1v * (1.f - p1v);
                tA[b * HID + tid] = acc[b] * p1v + u1s[b * HID + tid] * q1 * tB[b * HID + tid];
            }
        }
        __syncthreads();

        // T5: v0 = W1 d1dot ; d0dot = v0*p0 + u0*q0*t0 -> tA
        if (tid < HID) matvec_acc(W1T, tA, tid, acc);
        __syncthreads();
        if (tid < HID) {
#pragma unroll
            for (int b = 0; b < B; ++b) {
                float p0v = p0s[b * HID + tid];
                float q0  = p0v * (1.f - p0v);
                tA[b * HID + tid] = acc[b] * p0v + u0s[b * HID + tid] * q0 * w0k[k * HID + tid];
            }
        }
        __syncthreads();

        // T6: Hr[b][k][m] = sum_i W0[m,i] * d0dot[i]
        if (tid < B * ZDIM) {
            const int b = tid >> 4, m = tid & 15;
            float s = 0.f;
            for (int i = 0; i < HID; i += 4) {
                const float4 x  = *reinterpret_cast<const float4*>(tA + b * HID + i);
                const float4 wv = *reinterpret_cast<const float4*>(W0 + m * HID + i);
                s += x.x * wv.x + x.y * wv.y + x.z * wv.z + x.w * wv.w;
            }
            Hr[(b * D + k) * ZDIM + m] = s;
        }
        __syncthreads();
    }

    // ---- Epilogue: per-sample 8x8 solve (M diagonally dominant, no pivoting) ----
    if (tid < B) {
        const int b = tid;
        float M[D][D], F[D], v[D], a[D];
#pragma unroll
        for (int c = 0; c < D; ++c) v[c] = zsh[b * ZDIM + D + c];
#pragma unroll
        for (int r = 0; r < D; ++r) {
            float f = gsh[b * ZDIM + r];
#pragma unroll
            for (int c = 0; c < D; ++c) {
                M[r][c] = Hr[(b * D + r) * ZDIM + D + c] + ((r == c) ? 2.f * EPS : 0.f);
                f -= Hr[(b * D + r) * ZDIM + c] * v[c];
            }
            F[r] = f;
        }
#pragma unroll
        for (int col = 0; col < D; ++col) {
            const float inv = 1.f / M[col][col];
#pragma unroll
            for (int r = col + 1; r < D; ++r) {
                const float fac = M[r][col] * inv;
#pragma unroll
                for (int c = col + 1; c < D; ++c) M[r][c] -= fac * M[col][c];
                F[r] -= fac * F[col];
            }
        }
#pragma unroll
        for (int r = D - 1; r >= 0; --r) {
            float s = F[r];
#pragma unroll
            for (int c = r + 1; c < D; ++c) s -= M[r][c] * a[c];
            a[r] = s / M[r][r];
        }
        float* op = out + (size_t)(s0 + b) * ZDIM;
#pragma unroll
        for (int c = 0; c < D; ++c) { op[c] = v[c]; op[D + c] = a[c]; }
    }
}

extern "C" void kernel_launch(void* const* d_in, const int* in_sizes, int n_in,
                              void* d_out, int out_size, void* d_ws, size_t ws_size,
                              hipStream_t stream)
{
    const float* z  = (const float*)d_in[1];
    const float* W0 = (const float*)d_in[2];
    const float* b0 = (const float*)d_in[3];
    const float* W1 = (const float*)d_in[4];
    const float* b1 = (const float*)d_in[5];
    const float* W2 = (const float*)d_in[6];
    const float* b2 = (const float*)d_in[7];
    const float* W3 = (const float*)d_in[8];
    float* out = (float*)d_out;

    float* W1T = (float*)d_ws;
    float* W2T = W1T + HID * HID;

    const int n = in_sizes[1] / (2 * D);

    transpose_k<<<dim3((HID * HID + NTHREADS - 1) / NTHREADS), dim3(NTHREADS), 0, stream>>>(
        W1, W2, W1T, W2T);
    lnn_main<<<dim3(n / B), dim3(NTHREADS), 0, stream>>>(
        z, W0, b0, W1, b1, W2, b2, W3, W1T, W2T, out);
}

// Round 2
// 207.108 us; speedup vs baseline: 7.3970x; 7.3970x over previous
//
#include <hip/hip_runtime.h>
#include <math.h>

#define DD 8
#define ZD 16
#define HID 200
#define EPSL 0.1f
#define BS 16          // samples per block
#define NTHREADS 256
#define NKC 7          // K chunks of 32 (K padded 200->224)
#define NMT 13         // unit tiles of 16 (200 -> 208)
#define XSTR 216       // halfs per X row (bank-spread pad)
#define CSTR 208       // halfs per coeff row
#define NTAN 8

// scales to keep fp16 intermediates in normal range
#define KSC 1024.0f        // backward-chain scale
#define SSC 64.0f          // tangent-chain scale
#define INV_K (1.0f/1024.0f)
#define INV_KS (1.0f/65536.0f)

typedef _Float16 half8 __attribute__((ext_vector_type(8)));
typedef _Float16 half4v __attribute__((ext_vector_type(4)));
typedef float float4v __attribute__((ext_vector_type(4)));

#define S4 (NKC*NMT*64*8)          // 46592 halfs per big swizzled array
#define OFF_W1T 0                  // A[u][k] = W1[k][u]  (forward)
#define OFF_W2T (S4)               // A[u][k] = W2[k][u]  (forward)
#define OFF_W1  (2*S4)             // A[u][k] = W1[u][k]  (backward)
#define OFF_W2  (3*S4)             // A[u][k] = W2[u][k]  (backward)
#define OFF_W0T (4*S4)             // A[u][k<32] = W0[k][u], 13 mt, 1 kc
#define OFF_W0  (4*S4 + NMT*64*8)  // A[z][k] = W0[z][k], 1 mt, 7 kc
#define WS_HALFS (4*S4 + NMT*64*8 + NKC*64*8)

// ---------------------------------------------------------------------------
// Pre-swizzle weights into MFMA A-fragment order (fp16), zero-padded.
// ---------------------------------------------------------------------------
__global__ void prep(const float* __restrict__ W0, const float* __restrict__ W1,
                     const float* __restrict__ W2, _Float16* __restrict__ ws)
{
    int idx = blockIdx.x * 256 + threadIdx.x;
    if (idx >= WS_HALFS) return;
    float v = 0.f;
    if (idx < 4*S4) {
        int arr = idx / S4, e = idx % S4;
        int kc = e / (NMT*64*8); int r = e % (NMT*64*8);
        int mt = r / (64*8); r %= 64*8;
        int lane = r / 8, j = r % 8;
        int m = mt*16 + (lane & 15);
        int k = kc*32 + (lane >> 4)*8 + j;
        if (m < HID && k < HID) {
            if      (arr == 0) v = W1[k*HID + m];
            else if (arr == 1) v = W2[k*HID + m];
            else if (arr == 2) v = W1[m*HID + k];
            else               v = W2[m*HID + k];
        }
    } else if (idx < OFF_W0) {
        int e = idx - OFF_W0T;
        int mt = e / (64*8); int r = e % (64*8);
        int lane = r / 8, j = r % 8;
        int m = mt*16 + (lane & 15);
        int k = (lane >> 4)*8 + j;           // single K-chunk (K=16 pad 32)
        if (m < HID && k < ZD) v = W0[k*HID + m];
    } else {
        int e = idx - OFF_W0;
        int kc = e / (64*8); int r = e % (64*8);
        int lane = r / 8, j = r % 8;
        int m = (lane & 15);                 // z-dim (16)
        int k = kc*32 + (lane >> 4)*8 + j;
        if (k < HID) v = W0[m*HID + k];
    }
    ws[idx] = (_Float16)v;
}

// ---------------------------------------------------------------------------
__device__ __forceinline__ float4v ldc4(const _Float16* p) {
    half4v h = *(const half4v*)p;
    float4v f; f.x = (float)h.x; f.y = (float)h.y; f.z = (float)h.z; f.w = (float)h.w;
    return f;
}
__device__ __forceinline__ void sth4(_Float16* p, float a, float b, float c, float d) {
    half4v h; h.x = (_Float16)a; h.y = (_Float16)b; h.z = (_Float16)c; h.w = (_Float16)d;
    *(half4v*)p = h;
}
__device__ __forceinline__ void sig_sp(float x, float& sp, float& sg) {
    float e = __expf(-fabsf(x));
    float r = 1.0f / (1.0f + e);
    sg = (x >= 0.f) ? r : (1.0f - r);
    sp = fmaxf(x, 0.f) + __logf(1.f + e);
}

// matvec: acc[m][n] += A(mt0+m) x X(nt=n), K-loop over 7 chunks
template<int NTILES>
__device__ __forceinline__ void run_mv(const half8* __restrict__ Asw,
                                       const _Float16* Xsrc,
                                       int mt0, int mtc, int lane,
                                       float4v acc[4][NTILES])
{
    const int lm = lane & 15, q = lane >> 4;
#pragma unroll
    for (int m = 0; m < 4; ++m)
#pragma unroll
        for (int n = 0; n < NTILES; ++n)
            acc[m][n] = (float4v){0.f, 0.f, 0.f, 0.f};
    for (int kc = 0; kc < NKC; ++kc) {
        half8 a[4];
#pragma unroll
        for (int m = 0; m < 4; ++m)
            if (m < mtc) a[m] = Asw[(kc*NMT + mt0 + m)*64 + lane];
        half8 x[NTILES];
#pragma unroll
        for (int n = 0; n < NTILES; ++n)
            x[n] = *(const half8*)(Xsrc + (n*16 + lm)*XSTR + kc*32 + q*8);
#pragma unroll
        for (int m = 0; m < 4; ++m)
            if (m < mtc)
#pragma unroll
                for (int n = 0; n < NTILES; ++n)
                    acc[m][n] = __builtin_amdgcn_mfma_f32_16x16x32_f16(a[m], x[n], acc[m][n], 0, 0, 0);
    }
}

// ---------------------------------------------------------------------------
__global__ void __launch_bounds__(NTHREADS, 1)
lnn_main(const float* __restrict__ z,
         const float* __restrict__ W0, const float* __restrict__ b0,
         const float* __restrict__ b1, const float* __restrict__ b2,
         const float* __restrict__ W3,
         const _Float16* __restrict__ ws,
         float* __restrict__ out)
{
    __shared__ _Float16 Xt[128*XSTR];
    __shared__ _Float16 Xb[128*XSTR];
    __shared__ _Float16 Cf[5][16*CSTR];   // 0:p0 1:p1 2:c2*K 3:u1'(1-p1) 4:u0'p0(1-p0)
    __shared__ _Float16 Xz[16*40];
    __shared__ float gsh[256];            // [sample][z]
    __shared__ float Hr[128*16];          // [tan*16+sample][z]

    const int tid  = threadIdx.x;
    const int wave = tid >> 6;
    const int lane = tid & 63;
    const int lm   = lane & 15;
    const int q    = lane >> 4;
    const int s0   = blockIdx.x * BS;

    // mt partition per wave: {0-3},{4-6},{7-9},{10-12}
    const int mt0 = (wave == 0) ? 0 : (wave == 1) ? 4 : (wave == 2) ? 7 : 10;
    const int mtc = (wave == 0) ? 4 : 3;

    const half8* W1Tsw = (const half8*)(ws + OFF_W1T);
    const half8* W2Tsw = (const half8*)(ws + OFF_W2T);
    const half8* W1sw  = (const half8*)(ws + OFF_W1);
    const half8* W2sw  = (const half8*)(ws + OFF_W2);
    const half8* W0Tsw = (const half8*)(ws + OFF_W0T);
    const half8* W0sw  = (const half8*)(ws + OFF_W0);

    // ---- init: stage z (fp16, K padded to 32), zero X pad columns ----
    {
        int s = tid >> 4, k = tid & 15;
        if (tid < 256) {
            Xz[s*40 + k]      = (_Float16)z[(s0 + s)*ZD + k];
            Xz[s*40 + 16 + k] = (_Float16)0.f;
        }
        for (int idx = tid; idx < 128*16; idx += NTHREADS) {
            int r = idx >> 4, c = 200 + (idx & 15);
            Xt[r*XSTR + c] = (_Float16)0.f;
            Xb[r*XSTR + c] = (_Float16)0.f;
        }
    }
    __syncthreads();

    float4v acc1[4][1];

    // ================= F0: a0 = z@W0+b0 ; h0->Xt, p0->Cf0 =================
    {
#pragma unroll
        for (int m = 0; m < 4; ++m) acc1[m][0] = (float4v){0.f,0.f,0.f,0.f};
        half8 xz = *(const half8*)(Xz + lm*40 + q*8);
#pragma unroll
        for (int m = 0; m < 4; ++m)
            if (m < mtc) {
                half8 a = W0Tsw[(mt0 + m)*64 + lane];
                acc1[m][0] = __builtin_amdgcn_mfma_f32_16x16x32_f16(a, xz, acc1[m][0], 0, 0, 0);
            }
#pragma unroll
        for (int m = 0; m < 4; ++m)
            if (m < mtc) {
                int mt = mt0 + m, ub = mt*16 + q*4;
                bool pad = (mt == 12 && q >= 2);
                float4v bb = *(const float4v*)(b0 + ub);   // OOB-adjacent reads page-safe; zeroed below
                float h[4], p[4];
#pragma unroll
                for (int r = 0; r < 4; ++r) {
                    float a = acc1[m][0][r] + bb[r];
                    float sp, sg; sig_sp(a, sp, sg);
                    h[r] = pad ? 0.f : sp;
                    p[r] = pad ? 0.f : sg;
                }
                sth4(&Xt[lm*XSTR + ub], h[0], h[1], h[2], h[3]);
                sth4(&Cf[0][lm*CSTR + ub], p[0], p[1], p[2], p[3]);
            }
    }
    __syncthreads();

    // ================= F1: a1 = h0@W1+b1 ; h1->Xt, p1->Cf1 =================
    run_mv<1>(W1Tsw, Xt, mt0, mtc, lane, acc1);
    __syncthreads();
#pragma unroll
    for (int m = 0; m < 4; ++m)
        if (m < mtc) {
            int mt = mt0 + m, ub = mt*16 + q*4;
            bool pad = (mt == 12 && q >= 2);
            float4v bb = *(const float4v*)(b1 + ub);
            float h[4], p[4];
#pragma unroll
            for (int r = 0; r < 4; ++r) {
                float a = acc1[m][0][r] + bb[r];
                float sp, sg; sig_sp(a, sp, sg);
                h[r] = pad ? 0.f : sp;
                p[r] = pad ? 0.f : sg;
            }
            sth4(&Xt[lm*XSTR + ub], h[0], h[1], h[2], h[3]);
            sth4(&Cf[1][lm*CSTR + ub], p[0], p[1], p[2], p[3]);
        }
    __syncthreads();

    // ========= F2: a2 = h1@W2+b2 ; d2'=K*w3*sg ->Xt, c2'=K*w3*sg(1-sg)->Cf2 =========
    run_mv<1>(W2Tsw, Xt, mt0, mtc, lane, acc1);
    __syncthreads();
#pragma unroll
    for (int m = 0; m < 4; ++m)
        if (m < mtc) {
            int mt = mt0 + m, ub = mt*16 + q*4;
            bool pad = (mt == 12 && q >= 2);
            float4v bb = *(const float4v*)(b2 + ub);
            float4v w3 = *(const float4v*)(W3 + ub);
            float d2[4], c2[4];
#pragma unroll
            for (int r = 0; r < 4; ++r) {
                float a = acc1[m][0][r] + bb[r];
                float e = __expf(-fabsf(a));
                float rr = 1.f / (1.f + e);
                float sg = (a >= 0.f) ? rr : (1.f - rr);
                float wk = KSC * w3[r];
                d2[r] = pad ? 0.f : wk * sg;
                c2[r] = pad ? 0.f : wk * sg * (1.f - sg);
            }
            sth4(&Xt[lm*XSTR + ub], d2[0], d2[1], d2[2], d2[3]);
            sth4(&Cf[2][lm*CSTR + ub], c2[0], c2[1], c2[2], c2[3]);
        }
    __syncthreads();

    // ========= B1: u1' = W2 d2' ; d1'=u1'p1 ->Xt, Cf3=u1'(1-p1) =========
    run_mv<1>(W2sw, Xt, mt0, mtc, lane, acc1);
    __syncthreads();
#pragma unroll
    for (int m = 0; m < 4; ++m)
        if (m < mtc) {
            int mt = mt0 + m, ub = mt*16 + q*4;
            bool pad = (mt == 12 && q >= 2);
            float4v p1 = ldc4(&Cf[1][lm*CSTR + ub]);
            float d1[4], c3[4];
#pragma unroll
            for (int r = 0; r < 4; ++r) {
                float u1 = acc1[m][0][r];
                d1[r] = pad ? 0.f : u1 * p1[r];
                c3[r] = pad ? 0.f : u1 * (1.f - p1[r]);
            }
            sth4(&Xt[lm*XSTR + ub], d1[0], d1[1], d1[2], d1[3]);
            sth4(&Cf[3][lm*CSTR + ub], c3[0], c3[1], c3[2], c3[3]);
        }
    __syncthreads();

    // ========= B0: u0' = W1 d1' ; d0'=u0'p0 ->Xt, Cf4=u0'p0(1-p0) =========
    run_mv<1>(W1sw, Xt, mt0, mtc, lane, acc1);
    __syncthreads();
#pragma unroll
    for (int m = 0; m < 4; ++m)
        if (m < mtc) {
            int mt = mt0 + m, ub = mt*16 + q*4;
            bool pad = (mt == 12 && q >= 2);
            float4v p0 = ldc4(&Cf[0][lm*CSTR + ub]);
            float d0[4], c4[4];
#pragma unroll
            for (int r = 0; r < 4; ++r) {
                float u0 = acc1[m][0][r];
                d0[r] = pad ? 0.f : u0 * p0[r];
                c4[r] = pad ? 0.f : u0 * p0[r] * (1.f - p0[r]);
            }
            sth4(&Xt[lm*XSTR + ub], d0[0], d0[1], d0[2], d0[3]);
            sth4(&Cf[4][lm*CSTR + ub], c4[0], c4[1], c4[2], c4[3]);
        }
    __syncthreads();

    // ========= g-projection: g[z][sample] = W0 . d0  (wave 0 only) =========
    if (wave == 0) {
        float4v g = (float4v){0.f,0.f,0.f,0.f};
        for (int kc = 0; kc < NKC; ++kc) {
            half8 a = W0sw[kc*64 + lane];
            half8 x = *(const half8*)(Xt + lm*XSTR + kc*32 + q*8);
            g = __builtin_amdgcn_mfma_f32_16x16x32_f16(a, x, g, 0, 0, 0);
        }
        float4v gv; gv.x = g.x*INV_K; gv.y = g.y*INV_K; gv.z = g.z*INV_K; gv.w = g.w*INV_K;
        *(float4v*)(&gsh[lm*16 + q*4]) = gv;
    }
    __syncthreads();

    // ========= th0 build: Xt[t*16+s][u] = SSC * p0[s][u] * W0[8+t][u] =========
    for (int idx = tid; idx < 128*50; idx += NTHREADS) {
        int row = idx / 50, c4 = idx % 50;
        int u = c4 * 4;
        int t = row >> 4, s = row & 15;
        float4v p0 = ldc4(&Cf[0][s*CSTR + u]);
        float4v t0 = *(const float4v*)(W0 + (DD + t)*HID + u);
        sth4(&Xt[row*XSTR + u], SSC*p0.x*t0.x, SSC*p0.y*t0.y, SSC*p0.z*t0.z, SSC*p0.w*t0.w);
    }
    __syncthreads();

    float4v acc8[4][NTAN];

    // ========= T2: t1' = th0@W1 ; th1' = t1'*p1 -> Xb =========
    run_mv<NTAN>(W1Tsw, Xt, mt0, mtc, lane, acc8);
    __syncthreads();
#pragma unroll
    for (int m = 0; m < 4; ++m)
        if (m < mtc) {
            int mt = mt0 + m, ub = mt*16 + q*4;
            bool pad = (mt == 12 && q >= 2);
            float4v p1 = ldc4(&Cf[1][lm*CSTR + ub]);
#pragma unroll
            for (int n = 0; n < NTAN; ++n) {
                int row = n*16 + lm;
                float a0 = pad ? 0.f : acc8[m][n][0]*p1[0];
                float a1 = pad ? 0.f : acc8[m][n][1]*p1[1];
                float a2 = pad ? 0.f : acc8[m][n][2]*p1[2];
                float a3 = pad ? 0.f : acc8[m][n][3]*p1[3];
                sth4(&Xb[row*XSTR + ub], a0, a1, a2, a3);
            }
        }
    __syncthreads();

    // ========= T3: t2'' = th1'@W2 ; d2dot = c2' * t2'' -> Xt =========
    run_mv<NTAN>(W2Tsw, Xb, mt0, mtc, lane, acc8);
    __syncthreads();
#pragma unroll
    for (int m = 0; m < 4; ++m)
        if (m < mtc) {
            int mt = mt0 + m, ub = mt*16 + q*4;
            bool pad = (mt == 12 && q >= 2);
            float4v c2 = ldc4(&Cf[2][lm*CSTR + ub]);
#pragma unroll
            for (int n = 0; n < NTAN; ++n) {
                int row = n*16 + lm;
                float a0 = pad ? 0.f : acc8[m][n][0]*c2[0];
                float a1 = pad ? 0.f : acc8[m][n][1]*c2[1];
                float a2 = pad ? 0.f : acc8[m][n][2]*c2[2];
                float a3 = pad ? 0.f : acc8[m][n][3]*c2[3];
                sth4(&Xt[row*XSTR + ub], a0, a1, a2, a3);
            }
        }
    __syncthreads();

    // ========= T4: v1'' = W2 d2dot ; d1dot = v1''*p1 + Cf3*th1' -> Xt =========
    run_mv<NTAN>(W2sw, Xt, mt0, mtc, lane, acc8);
    __syncthreads();
#pragma unroll
    for (int m = 0; m < 4; ++m)
        if (m < mtc) {
            int mt = mt0 + m, ub = mt*16 + q*4;
            bool pad = (mt == 12 && q >= 2);
            float4v p1 = ldc4(&Cf[1][lm*CSTR + ub]);
            float4v c3 = ldc4(&Cf[3][lm*CSTR + ub]);
#pragma unroll
            for (int n = 0; n < NTAN; ++n) {
                int row = n*16 + lm;
                float4v th1 = ldc4(&Xb[row*XSTR + ub]);
                float a0 = pad ? 0.f : acc8[m][n][0]*p1[0] + c3[0]*th1[0];
                float a1 = pad ? 0.f : acc8[m][n][1]*p1[1] + c3[1]*th1[1];
                float a2 = pad ? 0.f : acc8[m][n][2]*p1[2] + c3[2]*th1[2];
                float a3 = pad ? 0.f : acc8[m][n][3]*p1[3] + c3[3]*th1[3];
                sth4(&Xt[row*XSTR + ub], a0, a1, a2, a3);
            }
        }
    __syncthreads();

    // ========= T5: v0'' = W1 d1dot ; d0dot = v0''*p0 + Cf4*(S*t0) -> Xb =========
    run_mv<NTAN>(W1sw, Xt, mt0, mtc, lane, acc8);
    __syncthreads();
#pragma unroll
    for (int m = 0; m < 4; ++m)
        if (m < mtc) {
            int mt = mt0 + m, ub = mt*16 + q*4;
            bool pad = (mt == 12 && q >= 2);
            float4v p0 = ldc4(&Cf[0][lm*CSTR + ub]);
            float4v c4 = ldc4(&Cf[4][lm*CSTR + ub]);
#pragma unroll
            for (int n = 0; n < NTAN; ++n) {
                int row = n*16 + lm;
                float4v t0 = *(const float4v*)(W0 + (DD + n)*HID + ub); // page-safe OOB at pad, zeroed
                float a0 = pad ? 0.f : acc8[m][n][0]*p0[0] + c4[0]*(SSC*t0[0]);
                float a1 = pad ? 0.f : acc8[m][n][1]*p0[1] + c4[1]*(SSC*t0[1]);
                float a2 = pad ? 0.f : acc8[m][n][2]*p0[2] + c4[2]*(SSC*t0[2]);
                float a3 = pad ? 0.f : acc8[m][n][3]*p0[3] + c4[3]*(SSC*t0[3]);
                sth4(&Xb[row*XSTR + ub], a0, a1, a2, a3);
            }
        }
    __syncthreads();

    // ========= Hr projection: Hr[row][z] = (W0 . d0dot)/(K*S), 2 nt per wave =========
    {
        float4v hacc[2];
        hacc[0] = (float4v){0.f,0.f,0.f,0.f};
        hacc[1] = (float4v){0.f,0.f,0.f,0.f};
        for (int kc = 0; kc < NKC; ++kc) {
            half8 a = W0sw[kc*64 + lane];
#pragma unroll
            for (int j = 0; j < 2; ++j) {
                int nt = wave*2 + j;
                half8 x = *(const half8*)(Xb + (nt*16 + lm)*XSTR + kc*32 + q*8);
                hacc[j] = __builtin_amdgcn_mfma_f32_16x16x32_f16(a, x, hacc[j], 0, 0, 0);
            }
        }
#pragma unroll
        for (int j = 0; j < 2; ++j) {
            int row = (wave*2 + j)*16 + lm;
            float4v hv;
            hv.x = hacc[j].x*INV_KS; hv.y = hacc[j].y*INV_KS;
            hv.z = hacc[j].z*INV_KS; hv.w = hacc[j].w*INV_KS;
            *(float4v*)(&Hr[row*16 + q*4]) = hv;
        }
    }
    __syncthreads();

    // ========= per-sample 8x8 solve =========
    if (tid < BS) {
        const int s = tid;
        float M[DD][DD], F[DD], v[DD], a[DD];
#pragma unroll
        for (int c = 0; c < DD; ++c) v[c] = z[(s0 + s)*ZD + DD + c];
#pragma unroll
        for (int r = 0; r < DD; ++r) {
            float f = gsh[s*16 + r];
#pragma unroll
            for (int c = 0; c < DD; ++c) {
                M[r][c] = Hr[(r*16 + s)*16 + DD + c] + ((r == c) ? 2.f*EPSL : 0.f);
                f -= Hr[(r*16 + s)*16 + c] * v[c];
            }
            F[r] = f;
        }
#pragma unroll
        for (int col = 0; col < DD; ++col) {
            const float inv = 1.f / M[col][col];
#pragma unroll
            for (int r = col + 1; r < DD; ++r) {
                const float fac = M[r][col] * inv;
#pragma unroll
                for (int c = col + 1; c < DD; ++c) M[r][c] -= fac * M[col][c];
                F[r] -= fac * F[col];
            }
        }
#pragma unroll
        for (int r = DD - 1; r >= 0; --r) {
            float ssum = F[r];
#pragma unroll
            for (int c = r + 1; c < DD; ++c) ssum -= M[r][c] * a[c];
            a[r] = ssum / M[r][r];
        }
        float* op = out + (size_t)(s0 + s)*ZD;
#pragma unroll
        for (int c = 0; c < DD; ++c) { op[c] = v[c]; op[DD + c] = a[c]; }
    }
}

extern "C" void kernel_launch(void* const* d_in, const int* in_sizes, int n_in,
                              void* d_out, int out_size, void* d_ws, size_t ws_size,
                              hipStream_t stream)
{
    const float* z  = (const float*)d_in[1];
    const float* W0 = (const float*)d_in[2];
    const float* b0 = (const float*)d_in[3];
    const float* W1 = (const float*)d_in[4];
    const float* b1 = (const float*)d_in[5];
    const float* W2 = (const float*)d_in[6];
    const float* b2 = (const float*)d_in[7];
    const float* W3 = (const float*)d_in[8];
    float* out = (float*)d_out;
    _Float16* ws = (_Float16*)d_ws;

    const int n = in_sizes[1] / (2*DD);

    prep<<<dim3((WS_HALFS + 255)/256), dim3(256), 0, stream>>>(W0, W1, W2, ws);
    lnn_main<<<dim3(n / BS), dim3(NTHREADS), 0, stream>>>(
        z, W0, b0, b1, b2, W3, ws, out);
}

// Round 3
// 187.108 us; speedup vs baseline: 8.1876x; 1.1069x over previous
//
#include <hip/hip_runtime.h>
#include <math.h>

#define DD 8
#define ZD 16
#define HID 200
#define EPSL 0.1f
#define BS 16          // samples per block
#define NTHREADS 512   // 8 waves: 2 waves/SIMD for latency hiding
#define NKC 7          // K chunks of 32 (K padded 200->224)
#define NMT 13         // unit tiles of 16 (200 -> 208)
#define XSTR 216       // halfs per X row (108 dwords = 12 mod 32: minimal 2-way)
#define CSTR 212       // halfs per coeff row (106 dwords = 10 mod 32: conflict-free b64)
#define HSTR 20        // floats per Hr/gsh row (2-way instead of 8-way)
#define NTAN 8

// scales to keep fp16 intermediates in normal range
#define KSC 1024.0f        // backward-chain scale
#define SSC 64.0f          // tangent-chain scale
#define INV_K (1.0f/1024.0f)
#define INV_KS (1.0f/65536.0f)

typedef _Float16 half8 __attribute__((ext_vector_type(8)));
typedef _Float16 half4v __attribute__((ext_vector_type(4)));
typedef float float4v __attribute__((ext_vector_type(4)));

#define S4 (NKC*NMT*64*8)          // 46592 halfs per big swizzled array
#define OFF_W1T 0                  // A[u][k] = W1[k][u]  (forward)
#define OFF_W2T (S4)               // A[u][k] = W2[k][u]  (forward)
#define OFF_W1  (2*S4)             // A[u][k] = W1[u][k]  (backward)
#define OFF_W2  (3*S4)             // A[u][k] = W2[u][k]  (backward)
#define OFF_W0T (4*S4)             // A[u][k<32] = W0[k][u], 13 mt, 1 kc
#define OFF_W0  (4*S4 + NMT*64*8)  // A[z][k] = W0[z][k], 1 mt, 7 kc
#define WS_HALFS (4*S4 + NMT*64*8 + NKC*64*8)

// ---------------------------------------------------------------------------
// Pre-swizzle weights into MFMA A-fragment order (fp16), zero-padded.
// ---------------------------------------------------------------------------
__global__ void prep(const float* __restrict__ W0, const float* __restrict__ W1,
                     const float* __restrict__ W2, _Float16* __restrict__ ws)
{
    int idx = blockIdx.x * 256 + threadIdx.x;
    if (idx >= WS_HALFS) return;
    float v = 0.f;
    if (idx < 4*S4) {
        int arr = idx / S4, e = idx % S4;
        int kc = e / (NMT*64*8); int r = e % (NMT*64*8);
        int mt = r / (64*8); r %= 64*8;
        int lane = r / 8, j = r % 8;
        int m = mt*16 + (lane & 15);
        int k = kc*32 + (lane >> 4)*8 + j;
        if (m < HID && k < HID) {
            if      (arr == 0) v = W1[k*HID + m];
            else if (arr == 1) v = W2[k*HID + m];
            else if (arr == 2) v = W1[m*HID + k];
            else               v = W2[m*HID + k];
        }
    } else if (idx < OFF_W0) {
        int e = idx - OFF_W0T;
        int mt = e / (64*8); int r = e % (64*8);
        int lane = r / 8, j = r % 8;
        int m = mt*16 + (lane & 15);
        int k = (lane >> 4)*8 + j;           // single K-chunk (K=16 pad 32)
        if (m < HID && k < ZD) v = W0[k*HID + m];
    } else {
        int e = idx - OFF_W0;
        int kc = e / (64*8); int r = e % (64*8);
        int lane = r / 8, j = r % 8;
        int m = (lane & 15);                 // z-dim (16)
        int k = kc*32 + (lane >> 4)*8 + j;
        if (k < HID) v = W0[m*HID + k];
    }
    ws[idx] = (_Float16)v;
}

// ---------------------------------------------------------------------------
__device__ __forceinline__ float4v ldc4(const _Float16* p) {
    half4v h = *(const half4v*)p;
    float4v f; f.x = (float)h.x; f.y = (float)h.y; f.z = (float)h.z; f.w = (float)h.w;
    return f;
}
__device__ __forceinline__ void sth4(_Float16* p, float a, float b, float c, float d) {
    half4v h; h.x = (_Float16)a; h.y = (_Float16)b; h.z = (_Float16)c; h.w = (_Float16)d;
    *(half4v*)p = h;
}
__device__ __forceinline__ void sig_sp(float x, float& sp, float& sg) {
    float e = __expf(-fabsf(x));
    float r = 1.0f / (1.0f + e);
    sg = (x >= 0.f) ? r : (1.0f - r);
    sp = fmaxf(x, 0.f) + __logf(1.f + e);
}

// matvec: acc[m][n] += A(mt0+m) x X(nt=n), K-loop over 7 chunks. mtc <= 2.
template<int NTILES>
__device__ __forceinline__ void run_mv(const half8* __restrict__ Asw,
                                       const _Float16* Xsrc,
                                       int mt0, int mtc, int lane,
                                       float4v acc[2][NTILES])
{
    const int lm = lane & 15, q = lane >> 4;
#pragma unroll
    for (int m = 0; m < 2; ++m)
#pragma unroll
        for (int n = 0; n < NTILES; ++n)
            acc[m][n] = (float4v){0.f, 0.f, 0.f, 0.f};
    for (int kc = 0; kc < NKC; ++kc) {
        half8 a[2];
#pragma unroll
        for (int m = 0; m < 2; ++m)
            if (m < mtc) a[m] = Asw[(kc*NMT + mt0 + m)*64 + lane];
        half8 x[NTILES];
#pragma unroll
        for (int n = 0; n < NTILES; ++n)
            x[n] = *(const half8*)(Xsrc + (n*16 + lm)*XSTR + kc*32 + q*8);
#pragma unroll
        for (int m = 0; m < 2; ++m)
            if (m < mtc)
#pragma unroll
                for (int n = 0; n < NTILES; ++n)
                    acc[m][n] = __builtin_amdgcn_mfma_f32_16x16x32_f16(a[m], x[n], acc[m][n], 0, 0, 0);
    }
}

// ---------------------------------------------------------------------------
__global__ void __launch_bounds__(NTHREADS, 1)
lnn_main(const float* __restrict__ z,
         const float* __restrict__ W0, const float* __restrict__ b0,
         const float* __restrict__ b1, const float* __restrict__ b2,
         const float* __restrict__ W3,
         const _Float16* __restrict__ ws,
         float* __restrict__ out)
{
    __shared__ _Float16 Xt[128*XSTR];
    __shared__ _Float16 Xb[128*XSTR];
    __shared__ _Float16 Cf[5][16*CSTR];   // 0:p0 1:p1 2:c2*K 3:u1'(1-p1) 4:u0'p0(1-p0)
    __shared__ _Float16 Xz[16*40];
    __shared__ float gsh[16*HSTR];        // [sample][z]
    __shared__ float Hr[128*HSTR];        // [tan*16+sample][z]

    const int tid  = threadIdx.x;
    const int wave = tid >> 6;
    const int lane = tid & 63;
    const int lm   = lane & 15;
    const int q    = lane >> 4;
    const int s0   = blockIdx.x * BS;

    // mt partition over 8 waves: {2,2,2,2,2,1,1,1}
    const int mt0 = (wave < 5) ? wave*2 : (10 + (wave - 5));
    const int mtc = (wave < 5) ? 2 : 1;

    const half8* W1Tsw = (const half8*)(ws + OFF_W1T);
    const half8* W2Tsw = (const half8*)(ws + OFF_W2T);
    const half8* W1sw  = (const half8*)(ws + OFF_W1);
    const half8* W2sw  = (const half8*)(ws + OFF_W2);
    const half8* W0Tsw = (const half8*)(ws + OFF_W0T);
    const half8* W0sw  = (const half8*)(ws + OFF_W0);

    // ---- init: stage z (fp16, K padded to 32), zero X pad columns ----
    {
        if (tid < 256) {
            int s = tid >> 4, k = tid & 15;
            Xz[s*40 + k]      = (_Float16)z[(s0 + s)*ZD + k];
            Xz[s*40 + 16 + k] = (_Float16)0.f;
        }
        for (int idx = tid; idx < 128*16; idx += NTHREADS) {
            int r = idx >> 4, c = 200 + (idx & 15);
            Xt[r*XSTR + c] = (_Float16)0.f;
            Xb[r*XSTR + c] = (_Float16)0.f;
        }
    }
    __syncthreads();

    float4v acc1[2][1];

    // ================= F0: a0 = z@W0+b0 ; h0->Xt, p0->Cf0 =================
    {
#pragma unroll
        for (int m = 0; m < 2; ++m) acc1[m][0] = (float4v){0.f,0.f,0.f,0.f};
        half8 xz = *(const half8*)(Xz + lm*40 + q*8);
#pragma unroll
        for (int m = 0; m < 2; ++m)
            if (m < mtc) {
                half8 a = W0Tsw[(mt0 + m)*64 + lane];
                acc1[m][0] = __builtin_amdgcn_mfma_f32_16x16x32_f16(a, xz, acc1[m][0], 0, 0, 0);
            }
#pragma unroll
        for (int m = 0; m < 2; ++m)
            if (m < mtc) {
                int mt = mt0 + m, ub = mt*16 + q*4;
                bool pad = (mt == 12 && q >= 2);
                float4v bb = *(const float4v*)(b0 + ub);   // OOB-adjacent reads page-safe; zeroed below
                float h[4], p[4];
#pragma unroll
                for (int r = 0; r < 4; ++r) {
                    float a = acc1[m][0][r] + bb[r];
                    float sp, sg; sig_sp(a, sp, sg);
                    h[r] = pad ? 0.f : sp;
                    p[r] = pad ? 0.f : sg;
                }
                sth4(&Xt[lm*XSTR + ub], h[0], h[1], h[2], h[3]);
                sth4(&Cf[0][lm*CSTR + ub], p[0], p[1], p[2], p[3]);
            }
    }
    __syncthreads();

    // ================= F1: a1 = h0@W1+b1 ; h1->Xt, p1->Cf1 =================
    run_mv<1>(W1Tsw, Xt, mt0, mtc, lane, acc1);
    __syncthreads();
#pragma unroll
    for (int m = 0; m < 2; ++m)
        if (m < mtc) {
            int mt = mt0 + m, ub = mt*16 + q*4;
            bool pad = (mt == 12 && q >= 2);
            float4v bb = *(const float4v*)(b1 + ub);
            float h[4], p[4];
#pragma unroll
            for (int r = 0; r < 4; ++r) {
                float a = acc1[m][0][r] + bb[r];
                float sp, sg; sig_sp(a, sp, sg);
                h[r] = pad ? 0.f : sp;
                p[r] = pad ? 0.f : sg;
            }
            sth4(&Xt[lm*XSTR + ub], h[0], h[1], h[2], h[3]);
            sth4(&Cf[1][lm*CSTR + ub], p[0], p[1], p[2], p[3]);
        }
    __syncthreads();

    // ========= F2: a2 = h1@W2+b2 ; d2'=K*w3*sg ->Xt, c2'=K*w3*sg(1-sg)->Cf2 =========
    run_mv<1>(W2Tsw, Xt, mt0, mtc, lane, acc1);
    __syncthreads();
#pragma unroll
    for (int m = 0; m < 2; ++m)
        if (m < mtc) {
            int mt = mt0 + m, ub = mt*16 + q*4;
            bool pad = (mt == 12 && q >= 2);
            float4v bb = *(const float4v*)(b2 + ub);
            float4v w3 = *(const float4v*)(W3 + ub);
            float d2[4], c2[4];
#pragma unroll
            for (int r = 0; r < 4; ++r) {
                float a = acc1[m][0][r] + bb[r];
                float e = __expf(-fabsf(a));
                float rr = 1.f / (1.f + e);
                float sg = (a >= 0.f) ? rr : (1.f - rr);
                float wk = KSC * w3[r];
                d2[r] = pad ? 0.f : wk * sg;
                c2[r] = pad ? 0.f : wk * sg * (1.f - sg);
            }
            sth4(&Xt[lm*XSTR + ub], d2[0], d2[1], d2[2], d2[3]);
            sth4(&Cf[2][lm*CSTR + ub], c2[0], c2[1], c2[2], c2[3]);
        }
    __syncthreads();

    // ========= B1: u1' = W2 d2' ; d1'=u1'p1 ->Xt, Cf3=u1'(1-p1) =========
    run_mv<1>(W2sw, Xt, mt0, mtc, lane, acc1);
    __syncthreads();
#pragma unroll
    for (int m = 0; m < 2; ++m)
        if (m < mtc) {
            int mt = mt0 + m, ub = mt*16 + q*4;
            bool pad = (mt == 12 && q >= 2);
            float4v p1 = ldc4(&Cf[1][lm*CSTR + ub]);
            float d1[4], c3[4];
#pragma unroll
            for (int r = 0; r < 4; ++r) {
                float u1 = acc1[m][0][r];
                d1[r] = pad ? 0.f : u1 * p1[r];
                c3[r] = pad ? 0.f : u1 * (1.f - p1[r]);
            }
            sth4(&Xt[lm*XSTR + ub], d1[0], d1[1], d1[2], d1[3]);
            sth4(&Cf[3][lm*CSTR + ub], c3[0], c3[1], c3[2], c3[3]);
        }
    __syncthreads();

    // ========= B0: u0' = W1 d1' ; d0'=u0'p0 ->Xt, Cf4=u0'p0(1-p0) =========
    run_mv<1>(W1sw, Xt, mt0, mtc, lane, acc1);
    __syncthreads();
#pragma unroll
    for (int m = 0; m < 2; ++m)
        if (m < mtc) {
            int mt = mt0 + m, ub = mt*16 + q*4;
            bool pad = (mt == 12 && q >= 2);
            float4v p0 = ldc4(&Cf[0][lm*CSTR + ub]);
            float d0[4], c4[4];
#pragma unroll
            for (int r = 0; r < 4; ++r) {
                float u0 = acc1[m][0][r];
                d0[r] = pad ? 0.f : u0 * p0[r];
                c4[r] = pad ? 0.f : u0 * p0[r] * (1.f - p0[r]);
            }
            sth4(&Xt[lm*XSTR + ub], d0[0], d0[1], d0[2], d0[3]);
            sth4(&Cf[4][lm*CSTR + ub], c4[0], c4[1], c4[2], c4[3]);
        }
    __syncthreads();

    // ========= g-projection: g[z][sample] = W0 . d0  (wave 0 only) =========
    if (wave == 0) {
        float4v g = (float4v){0.f,0.f,0.f,0.f};
        for (int kc = 0; kc < NKC; ++kc) {
            half8 a = W0sw[kc*64 + lane];
            half8 x = *(const half8*)(Xt + lm*XSTR + kc*32 + q*8);
            g = __builtin_amdgcn_mfma_f32_16x16x32_f16(a, x, g, 0, 0, 0);
        }
        float4v gv; gv.x = g.x*INV_K; gv.y = g.y*INV_K; gv.z = g.z*INV_K; gv.w = g.w*INV_K;
        *(float4v*)(&gsh[lm*HSTR + q*4]) = gv;
    }
    __syncthreads();

    // ========= th0 build: Xt[t*16+s][u] = SSC * p0[s][u] * W0[8+t][u] =========
    for (int idx = tid; idx < 128*50; idx += NTHREADS) {
        int row = idx / 50, c4 = idx % 50;
        int u = c4 * 4;
        int t = row >> 4, s = row & 15;
        float4v p0 = ldc4(&Cf[0][s*CSTR + u]);
        float4v t0 = *(const float4v*)(W0 + (DD + t)*HID + u);
        sth4(&Xt[row*XSTR + u], SSC*p0.x*t0.x, SSC*p0.y*t0.y, SSC*p0.z*t0.z, SSC*p0.w*t0.w);
    }
    __syncthreads();

    float4v acc8[2][NTAN];

    // ========= T2: t1' = th0@W1 ; th1' = t1'*p1 -> Xb =========
    run_mv<NTAN>(W1Tsw, Xt, mt0, mtc, lane, acc8);
    __syncthreads();
#pragma unroll
    for (int m = 0; m < 2; ++m)
        if (m < mtc) {
            int mt = mt0 + m, ub = mt*16 + q*4;
            bool pad = (mt == 12 && q >= 2);
            float4v p1 = ldc4(&Cf[1][lm*CSTR + ub]);
#pragma unroll
            for (int n = 0; n < NTAN; ++n) {
                int row = n*16 + lm;
                float a0 = pad ? 0.f : acc8[m][n][0]*p1[0];
                float a1 = pad ? 0.f : acc8[m][n][1]*p1[1];
                float a2 = pad ? 0.f : acc8[m][n][2]*p1[2];
                float a3 = pad ? 0.f : acc8[m][n][3]*p1[3];
                sth4(&Xb[row*XSTR + ub], a0, a1, a2, a3);
            }
        }
    __syncthreads();

    // ========= T3: t2'' = th1'@W2 ; d2dot = c2' * t2'' -> Xt =========
    run_mv<NTAN>(W2Tsw, Xb, mt0, mtc, lane, acc8);
    __syncthreads();
#pragma unroll
    for (int m = 0; m < 2; ++m)
        if (m < mtc) {
            int mt = mt0 + m, ub = mt*16 + q*4;
            bool pad = (mt == 12 && q >= 2);
            float4v c2 = ldc4(&Cf[2][lm*CSTR + ub]);
#pragma unroll
            for (int n = 0; n < NTAN; ++n) {
                int row = n*16 + lm;
                float a0 = pad ? 0.f : acc8[m][n][0]*c2[0];
                float a1 = pad ? 0.f : acc8[m][n][1]*c2[1];
                float a2 = pad ? 0.f : acc8[m][n][2]*c2[2];
                float a3 = pad ? 0.f : acc8[m][n][3]*c2[3];
                sth4(&Xt[row*XSTR + ub], a0, a1, a2, a3);
            }
        }
    __syncthreads();

    // ========= T4: v1'' = W2 d2dot ; d1dot = v1''*p1 + Cf3*th1' -> Xt =========
    run_mv<NTAN>(W2sw, Xt, mt0, mtc, lane, acc8);
    __syncthreads();
#pragma unroll
    for (int m = 0; m < 2; ++m)
        if (m < mtc) {
            int mt = mt0 + m, ub = mt*16 + q*4;
            bool pad = (mt == 12 && q >= 2);
            float4v p1 = ldc4(&Cf[1][lm*CSTR + ub]);
            float4v c3 = ldc4(&Cf[3][lm*CSTR + ub]);
#pragma unroll
            for (int n = 0; n < NTAN; ++n) {
                int row = n*16 + lm;
                float4v th1 = ldc4(&Xb[row*XSTR + ub]);
                float a0 = pad ? 0.f : acc8[m][n][0]*p1[0] + c3[0]*th1[0];
                float a1 = pad ? 0.f : acc8[m][n][1]*p1[1] + c3[1]*th1[1];
                float a2 = pad ? 0.f : acc8[m][n][2]*p1[2] + c3[2]*th1[2];
                float a3 = pad ? 0.f : acc8[m][n][3]*p1[3] + c3[3]*th1[3];
                sth4(&Xt[row*XSTR + ub], a0, a1, a2, a3);
            }
        }
    __syncthreads();

    // ========= T5: v0'' = W1 d1dot ; d0dot = v0''*p0 + Cf4*(S*t0) -> Xb =========
    run_mv<NTAN>(W1sw, Xt, mt0, mtc, lane, acc8);
    __syncthreads();
#pragma unroll
    for (int m = 0; m < 2; ++m)
        if (m < mtc) {
            int mt = mt0 + m, ub = mt*16 + q*4;
            bool pad = (mt == 12 && q >= 2);
            float4v p0 = ldc4(&Cf[0][lm*CSTR + ub]);
            float4v c4 = ldc4(&Cf[4][lm*CSTR + ub]);
#pragma unroll
            for (int n = 0; n < NTAN; ++n) {
                int row = n*16 + lm;
                float4v t0 = *(const float4v*)(W0 + (DD + n)*HID + ub); // page-safe OOB at pad, zeroed
                float a0 = pad ? 0.f : acc8[m][n][0]*p0[0] + c4[0]*(SSC*t0[0]);
                float a1 = pad ? 0.f : acc8[m][n][1]*p0[1] + c4[1]*(SSC*t0[1]);
                float a2 = pad ? 0.f : acc8[m][n][2]*p0[2] + c4[2]*(SSC*t0[2]);
                float a3 = pad ? 0.f : acc8[m][n][3]*p0[3] + c4[3]*(SSC*t0[3]);
                sth4(&Xb[row*XSTR + ub], a0, a1, a2, a3);
            }
        }
    __syncthreads();

    // ========= Hr projection: Hr[row][z] = (W0 . d0dot)/(K*S), 1 nt per wave =========
    {
        float4v hacc = (float4v){0.f,0.f,0.f,0.f};
        for (int kc = 0; kc < NKC; ++kc) {
            half8 a = W0sw[kc*64 + lane];
            half8 x = *(const half8*)(Xb + (wave*16 + lm)*XSTR + kc*32 + q*8);
            hacc = __builtin_amdgcn_mfma_f32_16x16x32_f16(a, x, hacc, 0, 0, 0);
        }
        int row = wave*16 + lm;
        float4v hv;
        hv.x = hacc.x*INV_KS; hv.y = hacc.y*INV_KS;
        hv.z = hacc.z*INV_KS; hv.w = hacc.w*INV_KS;
        *(float4v*)(&Hr[row*HSTR + q*4]) = hv;
    }
    __syncthreads();

    // ========= per-sample 8x8 solve =========
    if (tid < BS) {
        const int s = tid;
        float M[DD][DD], F[DD], v[DD], a[DD];
#pragma unroll
        for (int c = 0; c < DD; ++c) v[c] = z[(s0 + s)*ZD + DD + c];
#pragma unroll
        for (int r = 0; r < DD; ++r) {
            float f = gsh[s*HSTR + r];
#pragma unroll
            for (int c = 0; c < DD; ++c) {
                M[r][c] = Hr[(r*16 + s)*HSTR + DD + c] + ((r == c) ? 2.f*EPSL : 0.f);
                f -= Hr[(r*16 + s)*HSTR + c] * v[c];
            }
            F[r] = f;
        }
#pragma unroll
        for (int col = 0; col < DD; ++col) {
            const float inv = 1.f / M[col][col];
#pragma unroll
            for (int r = col + 1; r < DD; ++r) {
                const float fac = M[r][col] * inv;
#pragma unroll
                for (int c = col + 1; c < DD; ++c) M[r][c] -= fac * M[col][c];
                F[r] -= fac * F[col];
            }
        }
#pragma unroll
        for (int r = DD - 1; r >= 0; --r) {
            float ssum = F[r];
#pragma unroll
            for (int c = r + 1; c < DD; ++c) ssum -= M[r][c] * a[c];
            a[r] = ssum / M[r][r];
        }
        float* op = out + (size_t)(s0 + s)*ZD;
#pragma unroll
        for (int c = 0; c < DD; ++c) { op[c] = v[c]; op[DD + c] = a[c]; }
    }
}

extern "C" void kernel_launch(void* const* d_in, const int* in_sizes, int n_in,
                              void* d_out, int out_size, void* d_ws, size_t ws_size,
                              hipStream_t stream)
{
    const float* z  = (const float*)d_in[1];
    const float* W0 = (const float*)d_in[2];
    const float* b0 = (const float*)d_in[3];
    const float* W1 = (const float*)d_in[4];
    const float* b1 = (const float*)d_in[5];
    const float* W2 = (const float*)d_in[6];
    const float* b2 = (const float*)d_in[7];
    const float* W3 = (const float*)d_in[8];
    float* out = (float*)d_out;
    _Float16* ws = (_Float16*)d_ws;

    const int n = in_sizes[1] / (2*DD);

    prep<<<dim3((WS_HALFS + 255)/256), dim3(256), 0, stream>>>(W0, W1, W2, ws);
    lnn_main<<<dim3(n / BS), dim3(NTHREADS), 0, stream>>>(
        z, W0, b0, b1, b2, W3, ws, out);
}

// Round 5
// 159.855 us; speedup vs baseline: 9.5835x; 1.1705x over previous
//
#include <hip/hip_runtime.h>
#include <math.h>

#define DD 8
#define ZD 16
#define HID 200
#define EPSL 0.1f
#define BS 16          // samples per block
#define NTHREADS 1024  // 16 waves: 4 waves/SIMD
#define NKC 7          // K chunks of 32 (200 -> 224)
#define NMT 13         // unit tiles of 16 (200 -> 208)
#define XSTR 216       // halfs per X row
#define CSTR 212       // halfs per coeff row
#define HSTR 20        // floats per Hr/gsh row
#define WSTR 208       // halfs per staged-weight row
#define NTAN 8
#define NT4 4          // n-tiles per wave in T phase

#define KSC 1024.0f        // backward-chain scale
#define SSC 64.0f          // tangent-chain scale
#define INV_K (1.0f/1024.0f)
#define INV_KS (1.0f/65536.0f)

typedef _Float16 half8 __attribute__((ext_vector_type(8)));
typedef _Float16 half4v __attribute__((ext_vector_type(4)));
typedef _Float16 half2v __attribute__((ext_vector_type(2)));
typedef __fp16 fp16x2 __attribute__((ext_vector_type(2)));
typedef float float4v __attribute__((ext_vector_type(4)));

#define S4 (NKC*NMT*64*8)
#define OFF_W1T 0
#define OFF_W2T (S4)
#define OFF_W1  (2*S4)
#define OFF_W2  (3*S4)
#define OFF_W0T (4*S4)
#define OFF_W0  (4*S4 + NMT*64*8)
#define WS_HALFS (4*S4 + NMT*64*8 + NKC*64*8)

// ---------------------------------------------------------------------------
__global__ void prep(const float* __restrict__ W0, const float* __restrict__ W1,
                     const float* __restrict__ W2, _Float16* __restrict__ ws)
{
    int idx = blockIdx.x * 256 + threadIdx.x;
    if (idx >= WS_HALFS) return;
    float v = 0.f;
    if (idx < 4*S4) {
        int arr = idx / S4, e = idx % S4;
        int kc = e / (NMT*64*8); int r = e % (NMT*64*8);
        int mt = r / (64*8); r %= 64*8;
        int lane = r / 8, j = r % 8;
        int m = mt*16 + (lane & 15);
        int k = kc*32 + (lane >> 4)*8 + j;
        if (m < HID && k < HID) {
            if      (arr == 0) v = W1[k*HID + m];
            else if (arr == 1) v = W2[k*HID + m];
            else if (arr == 2) v = W1[m*HID + k];
            else               v = W2[m*HID + k];
        }
    } else if (idx < OFF_W0) {
        int e = idx - OFF_W0T;
        int mt = e / (64*8); int r = e % (64*8);
        int lane = r / 8, j = r % 8;
        int m = mt*16 + (lane & 15);
        int k = (lane >> 4)*8 + j;
        if (m < HID && k < ZD) v = W0[k*HID + m];
    } else {
        int e = idx - OFF_W0;
        int kc = e / (64*8); int r = e % (64*8);
        int lane = r / 8, j = r % 8;
        int m = (lane & 15);
        int k = kc*32 + (lane >> 4)*8 + j;
        if (k < HID) v = W0[m*HID + k];
    }
    ws[idx] = (_Float16)v;
}

// ---------------------------------------------------------------------------
__device__ __forceinline__ half4v pk4(float4v a) {
    half2v lo = __builtin_bit_cast(half2v, __builtin_amdgcn_cvt_pkrtz(a.x, a.y));
    half2v hi = __builtin_bit_cast(half2v, __builtin_amdgcn_cvt_pkrtz(a.z, a.w));
    return __builtin_shufflevector(lo, hi, 0, 1, 2, 3);
}
__device__ __forceinline__ void sig_sp(float x, float& sp, float& sg) {
    float e = __expf(-fabsf(x));
    float r = 1.0f / (1.0f + e);
    sg = (x >= 0.f) ? r : (1.0f - r);
    sp = fmaxf(x, 0.f) + __logf(1.f + e);
}

template<int NTILES>
__device__ __forceinline__ void run_mv(const half8* __restrict__ Asw,
                                       const _Float16* __restrict__ Xsrc,
                                       int mt0, int mtc, int lane,
                                       float4v acc[2][NTILES])
{
    const int lm = lane & 15, q = lane >> 4;
#pragma unroll
    for (int m = 0; m < 2; ++m)
#pragma unroll
        for (int n = 0; n < NTILES; ++n)
            acc[m][n] = (float4v){0.f, 0.f, 0.f, 0.f};
    for (int kc = 0; kc < NKC; ++kc) {
        half8 a[2];
#pragma unroll
        for (int m = 0; m < 2; ++m)
            if (m < mtc) a[m] = Asw[(kc*NMT + mt0 + m)*64 + lane];
        half8 x[NTILES];
#pragma unroll
        for (int n = 0; n < NTILES; ++n)
            x[n] = *(const half8*)(Xsrc + (n*16 + lm)*XSTR + kc*32 + q*8);
#pragma unroll
        for (int m = 0; m < 2; ++m)
            if (m < mtc)
#pragma unroll
                for (int n = 0; n < NTILES; ++n)
                    acc[m][n] = __builtin_amdgcn_mfma_f32_16x16x32_f16(a[m], x[n], acc[m][n], 0, 0, 0);
    }
}

// ---------------------------------------------------------------------------
__global__ void __launch_bounds__(NTHREADS, 4)
lnn_main(const float* __restrict__ z,
         const float* __restrict__ W0, const float* __restrict__ b0,
         const float* __restrict__ b1, const float* __restrict__ b2,
         const float* __restrict__ W3,
         const _Float16* __restrict__ ws,
         float* __restrict__ out)
{
    __shared__ alignas(16) _Float16 Xt[128*XSTR];
    __shared__ alignas(16) _Float16 Xb[128*XSTR];
    __shared__ alignas(16) _Float16 Cf[5][16*CSTR]; // 0:p0 1:p1 2:c2*K 3:u1'(1-p1) 4:u0'p0(1-p0)
    __shared__ alignas(16) _Float16 Xz[16*40];
    __shared__ alignas(16) _Float16 bsh[4*WSTR];    // b0,b1,b2,KSC*W3 (zero-padded)
    __shared__ alignas(16) _Float16 w0t[NTAN*WSTR]; // SSC*W0[8+t][u] (zero-padded)
    __shared__ alignas(16) float gsh[16*HSTR];
    __shared__ alignas(16) float Hr[128*HSTR];

    const int tid  = threadIdx.x;
    const int wave = tid >> 6;
    const int lane = tid & 63;
    const int lm   = lane & 15;
    const int q    = lane >> 4;
    const int s0   = blockIdx.x * BS;

    // T-phase wave grid: 8 m-groups x 2 n-groups
    const int twm  = wave >> 1;
    const int twn  = wave & 1;
    const int mt0t = (twm < 5) ? twm*2 : (twm + 5);
    const int mtct = (twm < 5) ? 2 : 1;

    const half8* W1Tsw = (const half8*)(ws + OFF_W1T);
    const half8* W2Tsw = (const half8*)(ws + OFF_W2T);
    const half8* W1sw  = (const half8*)(ws + OFF_W1);
    const half8* W2sw  = (const half8*)(ws + OFF_W2);
    const half8* W0Tsw = (const half8*)(ws + OFF_W0T);
    const half8* W0sw  = (const half8*)(ws + OFF_W0);

    // ---- init/staging ----
    if (tid < 256) {
        int s = tid >> 4, k = tid & 15;
        Xz[s*40 + k]      = (_Float16)z[(s0 + s)*ZD + k];
        Xz[s*40 + 16 + k] = (_Float16)0.f;
    }
    for (int idx = tid; idx < 128*16; idx += NTHREADS) {
        int r = idx >> 4, c = 200 + (idx & 15);
        Xt[r*XSTR + c] = (_Float16)0.f;
        Xb[r*XSTR + c] = (_Float16)0.f;
    }
    for (int idx = tid; idx < 4*WSTR; idx += NTHREADS) {
        int l = idx / WSTR, u = idx % WSTR;
        float v = 0.f;
        if (u < HID) {
            if      (l == 0) v = b0[u];
            else if (l == 1) v = b1[u];
            else if (l == 2) v = b2[u];
            else             v = KSC * W3[u];
        }
        bsh[idx] = (_Float16)v;
    }
    for (int idx = tid; idx < NTAN*WSTR; idx += NTHREADS) {
        int t = idx / WSTR, u = idx % WSTR;
        w0t[idx] = (_Float16)((u < HID) ? SSC * W0[(DD + t)*HID + u] : 0.f);
    }
    __syncthreads();

    float4v acc1[2][1];
    const int ubf = wave*16 + q*4;   // F-phase unit base (wave<13)

    // ================= F0: a0 = z@W0+b0 =================
    if (wave < NMT) {
        acc1[0][0] = (float4v){0.f,0.f,0.f,0.f};
        half8 xz = *(const half8*)(Xz + lm*40 + q*8);
        half8 a = W0Tsw[wave*64 + lane];
        acc1[0][0] = __builtin_amdgcn_mfma_f32_16x16x32_f16(a, xz, acc1[0][0], 0, 0, 0);
        half4v bb = *(const half4v*)(&bsh[0*WSTR + ubf]);
        float h[4], p[4];
#pragma unroll
        for (int r = 0; r < 4; ++r) {
            float av = acc1[0][0][r] + (float)bb[r];
            sig_sp(av, h[r], p[r]);
        }
        *(half4v*)(&Xt[lm*XSTR + ubf])     = pk4((float4v){h[0],h[1],h[2],h[3]});
        *(half4v*)(&Cf[0][lm*CSTR + ubf])  = pk4((float4v){p[0],p[1],p[2],p[3]});
    }
    __syncthreads();

    // ================= F1 =================
    if (wave < NMT) run_mv<1>(W1Tsw, Xt, wave, 1, lane, acc1);
    __syncthreads();
    if (wave < NMT) {
        half4v bb = *(const half4v*)(&bsh[1*WSTR + ubf]);
        float h[4], p[4];
#pragma unroll
        for (int r = 0; r < 4; ++r) {
            float av = acc1[0][0][r] + (float)bb[r];
            sig_sp(av, h[r], p[r]);
        }
        *(half4v*)(&Xt[lm*XSTR + ubf])    = pk4((float4v){h[0],h[1],h[2],h[3]});
        *(half4v*)(&Cf[1][lm*CSTR + ubf]) = pk4((float4v){p[0],p[1],p[2],p[3]});
    }
    __syncthreads();

    // ================= F2: d2'=K*w3*sg, c2'=K*w3*sg(1-sg) =================
    if (wave < NMT) run_mv<1>(W2Tsw, Xt, wave, 1, lane, acc1);
    __syncthreads();
    if (wave < NMT) {
        half4v bb = *(const half4v*)(&bsh[2*WSTR + ubf]);
        half4v w3 = *(const half4v*)(&bsh[3*WSTR + ubf]);
        float d2[4], c2[4];
#pragma unroll
        for (int r = 0; r < 4; ++r) {
            float av = acc1[0][0][r] + (float)bb[r];
            float e = __expf(-fabsf(av));
            float rr = 1.f / (1.f + e);
            float sg = (av >= 0.f) ? rr : (1.f - rr);
            float wk = (float)w3[r];
            d2[r] = wk * sg;
            c2[r] = wk * sg * (1.f - sg);
        }
        *(half4v*)(&Xt[lm*XSTR + ubf])    = pk4((float4v){d2[0],d2[1],d2[2],d2[3]});
        *(half4v*)(&Cf[2][lm*CSTR + ubf]) = pk4((float4v){c2[0],c2[1],c2[2],c2[3]});
    }
    __syncthreads();

    // ================= B1: u1'=W2 d2'; d1'=u1'p1; Cf3=u1'(1-p1) =================
    if (wave < NMT) run_mv<1>(W2sw, Xt, wave, 1, lane, acc1);
    __syncthreads();
    if (wave < NMT) {
        half4v p1 = *(const half4v*)(&Cf[1][lm*CSTR + ubf]);
        half4v u1 = pk4(acc1[0][0]);
        half4v one = {(_Float16)1.f,(_Float16)1.f,(_Float16)1.f,(_Float16)1.f};
        *(half4v*)(&Xt[lm*XSTR + ubf])    = u1 * p1;
        *(half4v*)(&Cf[3][lm*CSTR + ubf]) = u1 * (one - p1);
    }
    __syncthreads();

    // ================= B0: u0'=W1 d1'; d0'=u0'p0; Cf4=u0'p0(1-p0) =================
    if (wave < NMT) run_mv<1>(W1sw, Xt, wave, 1, lane, acc1);
    __syncthreads();
    if (wave < NMT) {
        half4v p0 = *(const half4v*)(&Cf[0][lm*CSTR + ubf]);
        half4v u0 = pk4(acc1[0][0]);
        half4v one = {(_Float16)1.f,(_Float16)1.f,(_Float16)1.f,(_Float16)1.f};
        half4v d0 = u0 * p0;
        *(half4v*)(&Xt[lm*XSTR + ubf])    = d0;
        *(half4v*)(&Cf[4][lm*CSTR + ubf]) = d0 * (one - p0);
    }
    __syncthreads();

    // ===== g-projection (wave 0) || th0 build (waves 1-15, -> Xb) =====
    if (wave == 0) {
        float4v g = (float4v){0.f,0.f,0.f,0.f};
        for (int kc = 0; kc < NKC; ++kc) {
            half8 a = W0sw[kc*64 + lane];
            half8 x = *(const half8*)(Xt + lm*XSTR + kc*32 + q*8);
            g = __builtin_amdgcn_mfma_f32_16x16x32_f16(a, x, g, 0, 0, 0);
        }
        float4v gv; gv.x = g.x*INV_K; gv.y = g.y*INV_K; gv.z = g.z*INV_K; gv.w = g.w*INV_K;
        *(float4v*)(&gsh[lm*HSTR + q*4]) = gv;
    } else {
        for (int idx = tid - 64; idx < 128*50; idx += NTHREADS - 64) {
            int row = idx / 50, u = (idx % 50)*4;
            int s = row & 15, t = row >> 4;
            half4v p0 = *(const half4v*)(&Cf[0][s*CSTR + u]);
            half4v w0 = *(const half4v*)(&w0t[t*WSTR + u]);
            *(half4v*)(&Xb[row*XSTR + u]) = p0 * w0;
        }
    }
    __syncthreads();

    float4v acc4[2][NT4];

    // ========= T2: t1' = th0@W1 ; th1' = t1'*p1 -> Xt =========
    run_mv<NT4>(W1Tsw, Xb + twn*64*XSTR, mt0t, mtct, lane, acc4);
    __syncthreads();
#pragma unroll
    for (int m = 0; m < 2; ++m)
        if (m < mtct) {
            const int ub = (mt0t + m)*16 + q*4;
            half4v p1 = *(const half4v*)(&Cf[1][lm*CSTR + ub]);
#pragma unroll
            for (int n = 0; n < NT4; ++n) {
                int row = (twn*NT4 + n)*16 + lm;
                *(half4v*)(&Xt[row*XSTR + ub]) = pk4(acc4[m][n]) * p1;
            }
        }
    __syncthreads();

    // ========= T3: t2'' = th1'@W2 ; d2dot = c2'*t2'' -> Xb =========
    run_mv<NT4>(W2Tsw, Xt + twn*64*XSTR, mt0t, mtct, lane, acc4);
    __syncthreads();
#pragma unroll
    for (int m = 0; m < 2; ++m)
        if (m < mtct) {
            const int ub = (mt0t + m)*16 + q*4;
            half4v c2 = *(const half4v*)(&Cf[2][lm*CSTR + ub]);
#pragma unroll
            for (int n = 0; n < NT4; ++n) {
                int row = (twn*NT4 + n)*16 + lm;
                *(half4v*)(&Xb[row*XSTR + ub]) = pk4(acc4[m][n]) * c2;
            }
        }
    __syncthreads();

    // ========= T4: v1'' = W2 d2dot ; d1dot = v1''*p1 + c3*th1' -> Xb =========
    run_mv<NT4>(W2sw, Xb + twn*64*XSTR, mt0t, mtct, lane, acc4);
    __syncthreads();
#pragma unroll
    for (int m = 0; m < 2; ++m)
        if (m < mtct) {
            const int ub = (mt0t + m)*16 + q*4;
            half4v p1 = *(const half4v*)(&Cf[1][lm*CSTR + ub]);
            half4v c3 = *(const half4v*)(&Cf[3][lm*CSTR + ub]);
#pragma unroll
            for (int n = 0; n < NT4; ++n) {
                int row = (twn*NT4 + n)*16 + lm;
                half4v th1 = *(const half4v*)(&Xt[row*XSTR + ub]);
                *(half4v*)(&Xb[row*XSTR + ub]) = pk4(acc4[m][n]) * p1 + c3 * th1;
            }
        }
    __syncthreads();

    // ========= T5: v0'' = W1 d1dot ; d0dot = v0''*p0 + c4*(S*t0) -> Xt =========
    run_mv<NT4>(W1sw, Xb + twn*64*XSTR, mt0t, mtct, lane, acc4);
    __syncthreads();
#pragma unroll
    for (int m = 0; m < 2; ++m)
        if (m < mtct) {
            const int ub = (mt0t + m)*16 + q*4;
            half4v p0 = *(const half4v*)(&Cf[0][lm*CSTR + ub]);
            half4v c4 = *(const half4v*)(&Cf[4][lm*CSTR + ub]);
#pragma unroll
            for (int n = 0; n < NT4; ++n) {
                int row = (twn*NT4 + n)*16 + lm;
                half4v w0 = *(const half4v*)(&w0t[(twn*NT4 + n)*WSTR + ub]);
                *(half4v*)(&Xt[row*XSTR + ub]) = pk4(acc4[m][n]) * p0 + c4 * w0;
            }
        }
    __syncthreads();

    // ========= Hr projection: waves 0-7, nt = wave =========
    if (wave < 8) {
        float4v hacc = (float4v){0.f,0.f,0.f,0.f};
        for (int kc = 0; kc < NKC; ++kc) {
            half8 a = W0sw[kc*64 + lane];
            half8 x = *(const half8*)(Xt + (wave*16 + lm)*XSTR + kc*32 + q*8);
            hacc = __builtin_amdgcn_mfma_f32_16x16x32_f16(a, x, hacc, 0, 0, 0);
        }
        int row = wave*16 + lm;
        float4v hv;
        hv.x = hacc.x*INV_KS; hv.y = hacc.y*INV_KS;
        hv.z = hacc.z*INV_KS; hv.w = hacc.w*INV_KS;
        *(float4v*)(&Hr[row*HSTR + q*4]) = hv;
    }
    __syncthreads();

    // ========= per-sample 8x8 solve =========
    if (tid < BS) {
        const int s = tid;
        float M[DD][DD], F[DD], v[DD], a[DD];
#pragma unroll
        for (int c = 0; c < DD; ++c) v[c] = z[(s0 + s)*ZD + DD + c];
#pragma unroll
        for (int r = 0; r < DD; ++r) {
            float f = gsh[s*HSTR + r];
#pragma unroll
            for (int c = 0; c < DD; ++c) {
                M[r][c] = Hr[(r*16 + s)*HSTR + DD + c] + ((r == c) ? 2.f*EPSL : 0.f);
                f -= Hr[(r*16 + s)*HSTR + c] * v[c];
            }
            F[r] = f;
        }
#pragma unroll
        for (int col = 0; col < DD; ++col) {
            const float inv = 1.f / M[col][col];
#pragma unroll
            for (int r = col + 1; r < DD; ++r) {
                const float fac = M[r][col] * inv;
#pragma unroll
                for (int c = col + 1; c < DD; ++c) M[r][c] -= fac * M[col][c];
                F[r] -= fac * F[col];
            }
        }
#pragma unroll
        for (int r = DD - 1; r >= 0; --r) {
            float ssum = F[r];
#pragma unroll
            for (int c = r + 1; c < DD; ++c) ssum -= M[r][c] * a[c];
            a[r] = ssum / M[r][r];
        }
        float* op = out + (size_t)(s0 + s)*ZD;
#pragma unroll
        for (int c = 0; c < DD; ++c) { op[c] = v[c]; op[DD + c] = a[c]; }
    }
}

extern "C" void kernel_launch(void* const* d_in, const int* in_sizes, int n_in,
                              void* d_out, int out_size, void* d_ws, size_t ws_size,
                              hipStream_t stream)
{
    const float* z  = (const float*)d_in[1];
    const float* W0 = (const float*)d_in[2];
    const float* b0 = (const float*)d_in[3];
    const float* W1 = (const float*)d_in[4];
    const float* b1 = (const float*)d_in[5];
    const float* W2 = (const float*)d_in[6];
    const float* b2 = (const float*)d_in[7];
    const float* W3 = (const float*)d_in[8];
    float* out = (float*)d_out;
    _Float16* ws = (_Float16*)d_ws;

    const int n = in_sizes[1] / (2*DD);

    prep<<<dim3((WS_HALFS + 255)/256), dim3(256), 0, stream>>>(W0, W1, W2, ws);
    lnn_main<<<dim3(n / BS), dim3(NTHREADS), 0, stream>>>(
        z, W0, b0, b1, b2, W3, ws, out);
}